// Round 3
// baseline (269.573 us; speedup 1.0000x reference)
//
#include <hip/hip_runtime.h>

#define HH 128
#define WW 128

typedef float vfloat4 __attribute__((ext_vector_type(4)));

// Per-batch constants packed as 8 floats: {mux, muy, P2, Q2, R2, C, pad, pad}
// out[b,y,x] = exp2(P2*dx^2 + Q2*dx*dy + R2*dy^2 + C)

__global__ __launch_bounds__(256) void setup_kernel(
    const float* __restrict__ moments, float* __restrict__ cst, int B) {
    int b = blockIdx.x * 256 + threadIdx.x;
    if (b >= B) return;
    const float* m = moments + (size_t)b * 6;

    const float sx = (float)(WW - 1);   // 127
    const float sy = (float)(HH - 1);   // 127
    const float L2E = 1.44269504088896340736f;  // log2(e)

    float mux = tanhf(m[0]) * (sx * 0.5f) + (sx * 0.5f);
    float muy = tanhf(m[1]) * (sy * 0.5f) + (sy * 0.5f);

    float t0 = fminf(fmaxf(tanhf(m[2]), 0.03f),   1.0f);
    float t1 = fminf(fmaxf(tanhf(m[3]), -0.999f), 0.999f);
    float t2 = fminf(fmaxf(tanhf(m[4]), 0.03f),   1.0f);

    float a  = t0 * (3.0f * sx);
    float bb = t1 * sqrtf(t0 * t2 * (9.0f * sx * sy));
    float c  = t2 * (3.0f * sy);

    float det  = a * c - bb * bb;
    float it   = 10.0f / (1.0f + expf(-m[5]));             // 10*sigmoid
    float norm = it / (6.28318530717958647692f * sqrtf(det));

    float k = -0.5f * L2E / det;      // folds -0.5, 1/det, ln->log2
    vfloat4 c0 = {mux, muy, c * k, -2.0f * bb * k};              // P2, Q2
    vfloat4 c1 = {a * k, __builtin_amdgcn_logf(norm), 0.0f, 0.0f}; // R2, C=log2(norm)

    vfloat4* o = (vfloat4*)(cst + (size_t)b * 8);
    o[0] = c0;
    o[1] = c1;
}

__global__ __launch_bounds__(256) void MomentsToImage_kernel(
    const float* __restrict__ cst, float* __restrict__ out) {
    const int b = blockIdx.x;
    const float* s = cst + (size_t)b * 8;   // uniform address -> s_load

    float mux = s[0], muy = s[1];
    float P2 = s[2], Q2 = s[3], R2 = s[4], C = s[5];

    vfloat4* out4 = (vfloat4*)(out + (size_t)b * (HH * WW));

    #pragma unroll
    for (int i = 0; i < 16; ++i) {
        int v = i * 256 + threadIdx.x;   // float4 index within the image
        int p = v << 2;                  // pixel index
        float dy = (float)(p >> 7) - muy;
        float dx = (float)(p & 127) - mux;

        float base = fmaf(R2 * dy, dy, C);   // R2*dy^2 + C
        float qdy  = Q2 * dy;

        vfloat4 o;
        float d0 = dx;
        o.x = __builtin_amdgcn_exp2f(fmaf(fmaf(P2, d0, qdy), d0, base));
        float d1 = dx + 1.0f;
        o.y = __builtin_amdgcn_exp2f(fmaf(fmaf(P2, d1, qdy), d1, base));
        float d2 = dx + 2.0f;
        o.z = __builtin_amdgcn_exp2f(fmaf(fmaf(P2, d2, qdy), d2, base));
        float d3 = dx + 3.0f;
        o.w = __builtin_amdgcn_exp2f(fmaf(fmaf(P2, d3, qdy), d3, base));
        __builtin_nontemporal_store(o, &out4[v]);
    }
}

extern "C" void kernel_launch(void* const* d_in, const int* in_sizes, int n_in,
                              void* d_out, int out_size, void* d_ws, size_t ws_size,
                              hipStream_t stream) {
    const float* moments = (const float*)d_in[0];
    float* out = (float*)d_out;
    float* cst = (float*)d_ws;           // B*8 floats = 128 KiB, fits ws
    int B = in_sizes[0] / 6;             // 4096

    setup_kernel<<<dim3((B + 255) / 256), dim3(256), 0, stream>>>(moments, cst, B);
    MomentsToImage_kernel<<<dim3(B), dim3(256), 0, stream>>>(cst, out);
}

// Round 4
// 253.199 us; speedup vs baseline: 1.0647x; 1.0647x over previous
//
#include <hip/hip_runtime.h>

#define HH 128
#define WW 128

typedef float vfloat4 __attribute__((ext_vector_type(4)));

// Single fused kernel: one block per batch element.
// out[b,y,x] = exp2(P2*dx^2 + Q2*dx*dy + R2*dy^2 + C), dx = x-mux, dy = y-muy.
// Per-block setup (~8 transcendentals) is redundant across threads but costs
// ~0.4 us chip-wide -- cheaper than a second dispatch + cst round-trip.
__global__ __launch_bounds__(256) void MomentsToImage_kernel(
    const float* __restrict__ moments, float* __restrict__ out) {
    const int b = blockIdx.x;
    const float* m = moments + (size_t)b * 6;

    const float sx = (float)(WW - 1);   // 127
    const float sy = (float)(HH - 1);   // 127
    const float L2E = 1.44269504088896340736f;  // log2(e)

    float m0 = m[0], m1 = m[1], m2 = m[2], m3 = m[3], m4 = m[4], m5 = m[5];

    float mux = tanhf(m0) * (sx * 0.5f) + (sx * 0.5f);
    float muy = tanhf(m1) * (sy * 0.5f) + (sy * 0.5f);

    float t0 = fminf(fmaxf(tanhf(m2), 0.03f),   1.0f);
    float t1 = fminf(fmaxf(tanhf(m3), -0.999f), 0.999f);
    float t2 = fminf(fmaxf(tanhf(m4), 0.03f),   1.0f);

    float a  = t0 * (3.0f * sx);
    float bb = t1 * sqrtf(t0 * t2 * (9.0f * sx * sy));
    float c  = t2 * (3.0f * sy);

    float det  = a * c - bb * bb;
    float it   = 10.0f / (1.0f + expf(-m5));               // 10*sigmoid
    float norm = it / (6.28318530717958647692f * sqrtf(det));

    float k  = -0.5f * L2E / det;        // folds -0.5, 1/det, ln->log2
    float P2 = c * k;                    // dx^2 coeff
    float Q2 = -2.0f * bb * k;           // dx*dy coeff
    float R2 = a * k;                    // dy^2 coeff
    float C  = __builtin_amdgcn_logf(norm);   // v_log_f32 = log2

    vfloat4* out4 = (vfloat4*)(out + (size_t)b * (HH * WW));

    #pragma unroll
    for (int i = 0; i < 16; ++i) {
        int v = i * 256 + threadIdx.x;   // float4 index within the image
        int p = v << 2;                  // pixel index
        float dy = (float)(p >> 7) - muy;
        float dx = (float)(p & 127) - mux;

        float base = fmaf(R2 * dy, dy, C);   // R2*dy^2 + C
        float qdy  = Q2 * dy;

        vfloat4 o;
        float d0 = dx;
        o.x = __builtin_amdgcn_exp2f(fmaf(fmaf(P2, d0, qdy), d0, base));
        float d1 = dx + 1.0f;
        o.y = __builtin_amdgcn_exp2f(fmaf(fmaf(P2, d1, qdy), d1, base));
        float d2 = dx + 2.0f;
        o.z = __builtin_amdgcn_exp2f(fmaf(fmaf(P2, d2, qdy), d2, base));
        float d3 = dx + 3.0f;
        o.w = __builtin_amdgcn_exp2f(fmaf(fmaf(P2, d3, qdy), d3, base));
        out4[v] = o;
    }
}

extern "C" void kernel_launch(void* const* d_in, const int* in_sizes, int n_in,
                              void* d_out, int out_size, void* d_ws, size_t ws_size,
                              hipStream_t stream) {
    const float* moments = (const float*)d_in[0];
    float* out = (float*)d_out;
    int B = in_sizes[0] / 6;             // 4096
    MomentsToImage_kernel<<<dim3(B), dim3(256), 0, stream>>>(moments, out);
}